// Round 2
// baseline (1466.141 us; speedup 1.0000x reference)
//
#include <hip/hip_runtime.h>
#include <math.h>

#define BATCH  4
#define SEQL   4096
#define DMODEL 1024
#define NSTATE 64
#define LN_EPS 1e-5f
#define TB     8    // time sub-block held in registers (scan kernel)
#define TSUB   16   // t-rows per block in the correction+LN kernel

// ---------------------------------------------------------------------------
// k_scan: per-(b, d, chunk) local scan with ZERO init. Emits
//   y_local[t,d] = sum_n C[d,n] * s_local[n,t,d] + D[d]*u[t,d]   -> d_out
//   f[b][j][n][d] = local final state of chunk j                  -> ws
// The cross-chunk part is added later by k_corr_ln.
// ---------------------------------------------------------------------------
__global__ __launch_bounds__(256, 4) void k_scan(const float* __restrict__ u,
                                                 const float* __restrict__ A_log,
                                                 const float* __restrict__ C,
                                                 const float* __restrict__ Dvec,
                                                 const float* __restrict__ delta,
                                                 float* __restrict__ f,
                                                 float* __restrict__ y,
                                                 int NCH, int T) {
    __shared__ float r_lds[NSTATE];
    __shared__ float c_lds[64 * 65];          // padded leading dim
    const int tid = threadIdx.x;
    const int wave = tid >> 6, lane = tid & 63;
    const int cpb = NCH >> 2;
    const int b   = blockIdx.x / (16 * cpb);
    const int rem = blockIdx.x % (16 * cpb);
    const int dt  = rem / cpb;
    const int jg  = rem % cpb;
    const int j   = (jg << 2) | wave;
    const int d   = (dt << 6) | lane;

    if (tid < NSTATE) {
        float A = -expf(A_log[tid]);
        r_lds[tid] = expf(delta[0] * A);
    }
    for (int k = tid; k < 64 * 64; k += 256) {
        int row = k >> 6, col = k & 63;
        c_lds[row * 65 + col] = C[(size_t)((dt << 6) + row) * NSTATE + col];
    }
    __syncthreads();

    float s[NSTATE];
#pragma unroll
    for (int n = 0; n < NSTATE; ++n) s[n] = 0.f;

    const float Dd = Dvec[d];
    const float* ub = u + ((size_t)b * SEQL + (size_t)j * T) * DMODEL + d;
    float*       yb = y + ((size_t)b * SEQL + (size_t)j * T) * DMODEL + d;
    const int ntb = T / TB;
    for (int tb = 0; tb < ntb; ++tb) {
        float ur[TB], yr[TB];
#pragma unroll
        for (int t = 0; t < TB; ++t) {
            ur[t] = ub[(size_t)(tb * TB + t) * DMODEL];
            yr[t] = 0.f;
        }
#pragma unroll
        for (int n = 0; n < NSTATE; ++n) {
            const float rn = r_lds[n];
            const float cn = c_lds[lane * 65 + n];
            float sn = s[n];
#pragma unroll
            for (int t = 0; t < TB; ++t) {
                sn = fmaf(rn, sn, ur[t]);
                yr[t] = fmaf(cn, sn, yr[t]);
            }
            s[n] = sn;
        }
#pragma unroll
        for (int t = 0; t < TB; ++t)
            yb[(size_t)(tb * TB + t) * DMODEL] = fmaf(Dd, ur[t], yr[t]);
    }
    float* fb = f + (((size_t)b * NCH + j) * NSTATE) * DMODEL + d;
#pragma unroll
    for (int n = 0; n < NSTATE; ++n) fb[(size_t)n * DMODEL] = s[n];
}

// ---------------------------------------------------------------------------
// k_pass2: in-place scan over chunk boundaries. f[b][j][n][d] becomes
// I[b][j][n][d] = global state ENTERING chunk j. One thread per (b,n,d).
// ---------------------------------------------------------------------------
__global__ __launch_bounds__(256) void k_pass2(const float* __restrict__ A_log,
                                               const float* __restrict__ delta,
                                               float* __restrict__ f,
                                               int NCH, int T) {
    const int tid = blockIdx.x * 256 + threadIdx.x;  // over B*N*D
    const int d = tid & (DMODEL - 1);
    const int n = (tid >> 10) & (NSTATE - 1);
    const int b = tid >> 16;
    const float A  = -expf(A_log[n]);
    const float rT = expf((float)T * delta[0] * A);
    float I = 0.f;
    float* p = f + ((size_t)b * NCH * NSTATE + n) * DMODEL + d;
    const size_t stride = (size_t)NSTATE * DMODEL;
    for (int j = 0; j < NCH; ++j) {
        float tmp = p[(size_t)j * stride];
        p[(size_t)j * stride] = I;
        I = fmaf(rT, I, tmp);
    }
}

// ---------------------------------------------------------------------------
// k_corr_ln: per block = (b, 16 consecutive t rows) x ALL 1024 d.
//   corr[t,d] = sum_n rn^{tloc+1} * C[d,n] * I[n,d]
//   z = freq_align[d]*(y_local + corr) + (t==0 ? reward[d] : 0)
//   out = LayerNorm_d(z)*gamma + beta      (in-place on d_out)
// ---------------------------------------------------------------------------
__global__ __launch_bounds__(256) void k_corr_ln(float* __restrict__ y,
                                                 const float* __restrict__ A_log,
                                                 const float* __restrict__ C,
                                                 const float* __restrict__ delta,
                                                 const float* __restrict__ I,
                                                 const float* __restrict__ gamma,
                                                 const float* __restrict__ beta,
                                                 const float* __restrict__ fal,
                                                 const float* __restrict__ rw,
                                                 int NCH, int T) {
    const int tid = threadIdx.x;
    const int rows_per_seq = SEQL / TSUB;            // 256
    const int b     = blockIdx.x / rows_per_seq;
    const int row   = blockIdx.x % rows_per_seq;
    const int tbase = row * TSUB;
    const int j     = tbase / T;
    const int tloc0 = tbase % T;

    __shared__ float P[TSUB * NSTATE];               // P[t*64+n] = rn^{tloc0+t+1}
    __shared__ float red[2 * 4 * TSUB];

    const float d0v = delta[0];
    for (int i = tid; i < TSUB * NSTATE; i += 256) {
        int t = i >> 6, n = i & 63;
        float A = -expf(A_log[n]);
        P[i] = expf((float)(tloc0 + t + 1) * d0v * A);
    }
    __syncthreads();

    const int d0 = tid << 2;                          // 4 consecutive channels
    float acc[TSUB][4];
#pragma unroll
    for (int t = 0; t < TSUB; ++t)
#pragma unroll
        for (int k = 0; k < 4; ++k) acc[t][k] = 0.f;

    const float* Ibase = I + (((size_t)b * NCH + j) * NSTATE) * DMODEL + d0;
    for (int n0 = 0; n0 < NSTATE; n0 += 4) {
        float c_arr[4][4];
#pragma unroll
        for (int k = 0; k < 4; ++k) {
            float4 c4 = *(const float4*)&C[(size_t)(d0 + k) * NSTATE + n0];
            c_arr[k][0] = c4.x; c_arr[k][1] = c4.y; c_arr[k][2] = c4.z; c_arr[k][3] = c4.w;
        }
#pragma unroll
        for (int nn = 0; nn < 4; ++nn) {
            const int n = n0 + nn;
            float4 Iv = *(const float4*)&Ibase[(size_t)n * DMODEL];
            float J0 = c_arr[0][nn] * Iv.x;
            float J1 = c_arr[1][nn] * Iv.y;
            float J2 = c_arr[2][nn] * Iv.z;
            float J3 = c_arr[3][nn] * Iv.w;
#pragma unroll
            for (int t = 0; t < TSUB; ++t) {
                const float p = P[(t << 6) | n];
                acc[t][0] = fmaf(p, J0, acc[t][0]);
                acc[t][1] = fmaf(p, J1, acc[t][1]);
                acc[t][2] = fmaf(p, J2, acc[t][2]);
                acc[t][3] = fmaf(p, J3, acc[t][3]);
            }
        }
    }

    const float4 fa = *(const float4*)&fal[d0];
    const float4 rwv = *(const float4*)&rw[d0];
    float* ybase = y + ((size_t)b * SEQL + tbase) * DMODEL + d0;
    float sums[TSUB], sqs[TSUB];
#pragma unroll
    for (int t = 0; t < TSUB; ++t) {
        float4 v = *(const float4*)&ybase[(size_t)t * DMODEL];
        float z0 = fa.x * (v.x + acc[t][0]);
        float z1 = fa.y * (v.y + acc[t][1]);
        float z2 = fa.z * (v.z + acc[t][2]);
        float z3 = fa.w * (v.w + acc[t][3]);
        if (tbase + t == 0) { z0 += rwv.x; z1 += rwv.y; z2 += rwv.z; z3 += rwv.w; }
        acc[t][0] = z0; acc[t][1] = z1; acc[t][2] = z2; acc[t][3] = z3;
        sums[t] = z0 + z1 + z2 + z3;
        sqs[t]  = z0*z0 + z1*z1 + z2*z2 + z3*z3;
    }
    const int wave = tid >> 6, lane = tid & 63;
#pragma unroll
    for (int t = 0; t < TSUB; ++t) {
        float s = sums[t], q = sqs[t];
#pragma unroll
        for (int off = 32; off > 0; off >>= 1) {
            s += __shfl_down(s, off, 64);
            q += __shfl_down(q, off, 64);
        }
        if (lane == 0) { red[wave * TSUB + t] = s; red[4 * TSUB + wave * TSUB + t] = q; }
    }
    __syncthreads();
    const float4 g  = *(const float4*)&gamma[d0];
    const float4 bb = *(const float4*)&beta[d0];
#pragma unroll
    for (int t = 0; t < TSUB; ++t) {
        float s = red[t] + red[TSUB + t] + red[2 * TSUB + t] + red[3 * TSUB + t];
        float q = red[4 * TSUB + t] + red[5 * TSUB + t] + red[6 * TSUB + t] + red[7 * TSUB + t];
        const float mean = s * (1.f / DMODEL);
        const float var  = q * (1.f / DMODEL) - mean * mean;
        const float inv  = 1.f / sqrtf(var + LN_EPS);
        float4 o;
        o.x = (acc[t][0] - mean) * inv * g.x + bb.x;
        o.y = (acc[t][1] - mean) * inv * g.y + bb.y;
        o.z = (acc[t][2] - mean) * inv * g.z + bb.z;
        o.w = (acc[t][3] - mean) * inv * g.w + bb.w;
        *(float4*)&ybase[(size_t)t * DMODEL] = o;
    }
}

// ---------------------------------------------------------------------------
// k_state: final_state[b,n] = ((exp(dmean*A_n)-1)/A_safe_n) *
//                             sum_d B[n,d] * u[b, L-1, d]
// ---------------------------------------------------------------------------
__global__ __launch_bounds__(256) void k_state(const float* __restrict__ u,
                                               const float* __restrict__ A_log,
                                               const float* __restrict__ B,
                                               const float* __restrict__ delta,
                                               float* __restrict__ out) {
    const int n = blockIdx.x & 63;
    const int b = blockIdx.x >> 6;
    const int tid = threadIdx.x;
    const float* ul = u + ((size_t)b * SEQL + (SEQL - 1)) * DMODEL;
    const float* Bn = B + (size_t)n * DMODEL;
    float dot = 0.f, dsum = 0.f;
    for (int dd = tid; dd < DMODEL; dd += 256) {
        dot = fmaf(Bn[dd], ul[dd], dot);
        dsum += delta[dd];
    }
#pragma unroll
    for (int off = 32; off > 0; off >>= 1) {
        dot  += __shfl_down(dot,  off, 64);
        dsum += __shfl_down(dsum, off, 64);
    }
    __shared__ float red[8];
    const int wave = tid >> 6, lane = tid & 63;
    if (lane == 0) { red[wave] = dot; red[4 + wave] = dsum; }
    __syncthreads();
    if (tid == 0) {
        dot  = red[0] + red[1] + red[2] + red[3];
        dsum = red[4] + red[5] + red[6] + red[7];
        const float dmean = dsum * (1.f / DMODEL);
        const float A = -expf(A_log[n]);
        const float Abar = expf(dmean * A);
        const float Asafe = A + (A >= 0.f ? 1e-8f : -1e-8f);
        out[blockIdx.x] = ((Abar - 1.f) / Asafe) * dot;
    }
}

extern "C" void kernel_launch(void* const* d_in, const int* in_sizes, int n_in,
                              void* d_out, int out_size, void* d_ws, size_t ws_size,
                              hipStream_t stream) {
    const float* u     = (const float*)d_in[0];
    const float* A_log = (const float*)d_in[1];
    const float* B     = (const float*)d_in[2];
    const float* C     = (const float*)d_in[3];
    const float* Dv    = (const float*)d_in[4];
    const float* delta = (const float*)d_in[5];
    const float* gamma = (const float*)d_in[6];
    const float* beta  = (const float*)d_in[7];
    const float* fal   = (const float*)d_in[8];
    const float* rw    = (const float*)d_in[9];

    float* y  = (float*)d_out;
    float* st = y + (size_t)BATCH * SEQL * DMODEL;
    float* f  = (float*)d_ws;

    int NCH = 32;
    while (NCH > 4 && (size_t)BATCH * NCH * NSTATE * DMODEL * sizeof(float) > ws_size)
        NCH >>= 1;
    const int T = SEQL / NCH;

    const dim3 blk(256);
    const int nb1 = BATCH * (DMODEL / 64) * (NCH / 4);

    hipLaunchKernelGGL(k_scan, dim3(nb1), blk, 0, stream, u, A_log, C, Dv, delta, f, y, NCH, T);
    hipLaunchKernelGGL(k_pass2, dim3(BATCH * NSTATE * DMODEL / 256), blk, 0, stream,
                       A_log, delta, f, NCH, T);
    hipLaunchKernelGGL(k_corr_ln, dim3(BATCH * (SEQL / TSUB)), blk, 0, stream,
                       y, A_log, C, delta, f, gamma, beta, fal, rw, NCH, T);
    hipLaunchKernelGGL(k_state, dim3(BATCH * NSTATE), blk, 0, stream, u, A_log, B, delta, st);
}

// Round 3
// 195.428 us; speedup vs baseline: 7.5022x; 7.5022x over previous
//
#include <hip/hip_runtime.h>
#include <math.h>

#define BATCH  4
#define SEQL   4096
#define DMODEL 1024
#define NSTATE 64
#define LN_EPS 1e-5f
#define TB     8    // time sub-block held in registers (scan kernel)
#define TSUB   16   // t-rows per block in the correction+LN kernel
#define CPAD   68   // padded leading dim for C in LDS (16B-aligned rows)

// ---------------------------------------------------------------------------
// k_scan: per-(b, d, chunk) local scan with ZERO init. Emits
//   y_local[t,d] = sum_n C[d,n] * s_local[n,t,d] + D[d]*u[t,d]   -> d_out
//   f[b][j][n][d] = local final state of chunk j                  -> ws
// Inner loop: n-quads, 4 interleaved recurrence chains for ILP,
// float4 LDS reads for r and C.
// ---------------------------------------------------------------------------
__global__ __launch_bounds__(256) void k_scan(const float* __restrict__ u,
                                              const float* __restrict__ A_log,
                                              const float* __restrict__ C,
                                              const float* __restrict__ Dvec,
                                              const float* __restrict__ delta,
                                              float* __restrict__ f,
                                              float* __restrict__ y,
                                              int NCH, int T) {
    __shared__ __align__(16) float r_lds[NSTATE];
    __shared__ __align__(16) float c_lds[64 * CPAD];
    const int tid = threadIdx.x;
    const int wave = tid >> 6, lane = tid & 63;
    const int cpb = NCH >> 2;
    const int b   = blockIdx.x / (16 * cpb);
    const int rem = blockIdx.x % (16 * cpb);
    const int dt  = rem / cpb;
    const int jg  = rem % cpb;
    const int j   = (jg << 2) | wave;
    const int d   = (dt << 6) | lane;

    if (tid < NSTATE) {
        float A = -expf(A_log[tid]);
        r_lds[tid] = expf(delta[0] * A);
    }
    // C tile: 64 rows (d) x 64 cols (n), vectorized load, padded store
    for (int k = tid; k < 64 * 16; k += 256) {
        int row = k >> 4, col4 = (k & 15) << 2;
        float4 c4 = *(const float4*)&C[(size_t)((dt << 6) + row) * NSTATE + col4];
        *(float4*)&c_lds[row * CPAD + col4] = c4;
    }
    __syncthreads();

    float s[NSTATE];
#pragma unroll
    for (int n = 0; n < NSTATE; ++n) s[n] = 0.f;

    const float Dd = Dvec[d];
    const float* ub = u + ((size_t)b * SEQL + (size_t)j * T) * DMODEL + d;
    float*       yb = y + ((size_t)b * SEQL + (size_t)j * T) * DMODEL + d;
    const int ntb = T / TB;
    for (int tb = 0; tb < ntb; ++tb) {
        float ur[TB], yr[TB];
#pragma unroll
        for (int t = 0; t < TB; ++t) {
            ur[t] = ub[(size_t)(tb * TB + t) * DMODEL];
            yr[t] = 0.f;
        }
#pragma unroll
        for (int n0 = 0; n0 < NSTATE; n0 += 4) {
            const float4 r4 = *(const float4*)&r_lds[n0];
            const float4 c4 = *(const float4*)&c_lds[lane * CPAD + n0];
            float s0 = s[n0], s1 = s[n0 + 1], s2 = s[n0 + 2], s3 = s[n0 + 3];
#pragma unroll
            for (int t = 0; t < TB; ++t) {
                const float ut = ur[t];
                s0 = fmaf(r4.x, s0, ut);
                s1 = fmaf(r4.y, s1, ut);
                s2 = fmaf(r4.z, s2, ut);
                s3 = fmaf(r4.w, s3, ut);
                float acc = fmaf(c4.x, s0, yr[t]);
                acc = fmaf(c4.y, s1, acc);
                acc = fmaf(c4.z, s2, acc);
                yr[t] = fmaf(c4.w, s3, acc);
            }
            s[n0] = s0; s[n0 + 1] = s1; s[n0 + 2] = s2; s[n0 + 3] = s3;
        }
#pragma unroll
        for (int t = 0; t < TB; ++t)
            yb[(size_t)(tb * TB + t) * DMODEL] = fmaf(Dd, ur[t], yr[t]);
    }
    float* fb = f + (((size_t)b * NCH + j) * NSTATE) * DMODEL + d;
#pragma unroll
    for (int n = 0; n < NSTATE; ++n) fb[(size_t)n * DMODEL] = s[n];
}

// ---------------------------------------------------------------------------
// k_pass2: in-place scan over chunk boundaries. f[b][j][n][d] becomes
// I[b][j][n][d] = global state ENTERING chunk j. One thread per (b,n,d).
// ---------------------------------------------------------------------------
__global__ __launch_bounds__(256) void k_pass2(const float* __restrict__ A_log,
                                               const float* __restrict__ delta,
                                               float* __restrict__ f,
                                               int NCH, int T) {
    const int tid = blockIdx.x * 256 + threadIdx.x;  // over B*N*D
    const int d = tid & (DMODEL - 1);
    const int n = (tid >> 10) & (NSTATE - 1);
    const int b = tid >> 16;
    const float A  = -expf(A_log[n]);
    const float rT = expf((float)T * delta[0] * A);
    float I = 0.f;
    float* p = f + ((size_t)b * NCH * NSTATE + n) * DMODEL + d;
    const size_t stride = (size_t)NSTATE * DMODEL;
    for (int j = 0; j < NCH; ++j) {
        float tmp = p[(size_t)j * stride];
        p[(size_t)j * stride] = I;
        I = fmaf(rT, I, tmp);
    }
}

// ---------------------------------------------------------------------------
// k_corr_ln: per block = (b, 16 consecutive t rows) x ALL 1024 d.
//   corr[t,d] = sum_n rn^{tloc+1} * C[d,n] * I[n,d]
//   z = freq_align[d]*(y_local + corr) + (t==0 ? reward[d] : 0)
//   out = LayerNorm_d(z)*gamma + beta      (in-place on d_out)
// ---------------------------------------------------------------------------
__global__ __launch_bounds__(256) void k_corr_ln(float* __restrict__ y,
                                                 const float* __restrict__ A_log,
                                                 const float* __restrict__ C,
                                                 const float* __restrict__ delta,
                                                 const float* __restrict__ I,
                                                 const float* __restrict__ gamma,
                                                 const float* __restrict__ beta,
                                                 const float* __restrict__ fal,
                                                 const float* __restrict__ rw,
                                                 int NCH, int T) {
    const int tid = threadIdx.x;
    const int rows_per_seq = SEQL / TSUB;            // 256
    const int b     = blockIdx.x / rows_per_seq;
    const int row   = blockIdx.x % rows_per_seq;
    const int tbase = row * TSUB;
    const int j     = tbase / T;
    const int tloc0 = tbase % T;

    __shared__ float P[TSUB * NSTATE];               // P[t*64+n] = rn^{tloc0+t+1}
    __shared__ float red[2 * 4 * TSUB];

    const float d0v = delta[0];
    for (int i = tid; i < TSUB * NSTATE; i += 256) {
        int t = i >> 6, n = i & 63;
        float A = -expf(A_log[n]);
        P[i] = expf((float)(tloc0 + t + 1) * d0v * A);
    }
    __syncthreads();

    const int d0 = tid << 2;                          // 4 consecutive channels
    float acc[TSUB][4];
#pragma unroll
    for (int t = 0; t < TSUB; ++t)
#pragma unroll
        for (int k = 0; k < 4; ++k) acc[t][k] = 0.f;

    const float* Ibase = I + (((size_t)b * NCH + j) * NSTATE) * DMODEL + d0;
    for (int n0 = 0; n0 < NSTATE; n0 += 4) {
        float c_arr[4][4];
#pragma unroll
        for (int k = 0; k < 4; ++k) {
            float4 c4 = *(const float4*)&C[(size_t)(d0 + k) * NSTATE + n0];
            c_arr[k][0] = c4.x; c_arr[k][1] = c4.y; c_arr[k][2] = c4.z; c_arr[k][3] = c4.w;
        }
#pragma unroll
        for (int nn = 0; nn < 4; ++nn) {
            const int n = n0 + nn;
            float4 Iv = *(const float4*)&Ibase[(size_t)n * DMODEL];
            float J0 = c_arr[0][nn] * Iv.x;
            float J1 = c_arr[1][nn] * Iv.y;
            float J2 = c_arr[2][nn] * Iv.z;
            float J3 = c_arr[3][nn] * Iv.w;
#pragma unroll
            for (int t = 0; t < TSUB; ++t) {
                const float p = P[(t << 6) | n];
                acc[t][0] = fmaf(p, J0, acc[t][0]);
                acc[t][1] = fmaf(p, J1, acc[t][1]);
                acc[t][2] = fmaf(p, J2, acc[t][2]);
                acc[t][3] = fmaf(p, J3, acc[t][3]);
            }
        }
    }

    const float4 fa = *(const float4*)&fal[d0];
    const float4 rwv = *(const float4*)&rw[d0];
    float* ybase = y + ((size_t)b * SEQL + tbase) * DMODEL + d0;
    float sums[TSUB], sqs[TSUB];
#pragma unroll
    for (int t = 0; t < TSUB; ++t) {
        float4 v = *(const float4*)&ybase[(size_t)t * DMODEL];
        float z0 = fa.x * (v.x + acc[t][0]);
        float z1 = fa.y * (v.y + acc[t][1]);
        float z2 = fa.z * (v.z + acc[t][2]);
        float z3 = fa.w * (v.w + acc[t][3]);
        if (tbase + t == 0) { z0 += rwv.x; z1 += rwv.y; z2 += rwv.z; z3 += rwv.w; }
        acc[t][0] = z0; acc[t][1] = z1; acc[t][2] = z2; acc[t][3] = z3;
        sums[t] = z0 + z1 + z2 + z3;
        sqs[t]  = z0*z0 + z1*z1 + z2*z2 + z3*z3;
    }
    const int wave = tid >> 6, lane = tid & 63;
#pragma unroll
    for (int t = 0; t < TSUB; ++t) {
        float s = sums[t], q = sqs[t];
#pragma unroll
        for (int off = 32; off > 0; off >>= 1) {
            s += __shfl_down(s, off, 64);
            q += __shfl_down(q, off, 64);
        }
        if (lane == 0) { red[wave * TSUB + t] = s; red[4 * TSUB + wave * TSUB + t] = q; }
    }
    __syncthreads();
    const float4 g  = *(const float4*)&gamma[d0];
    const float4 bb = *(const float4*)&beta[d0];
#pragma unroll
    for (int t = 0; t < TSUB; ++t) {
        float s = red[t] + red[TSUB + t] + red[2 * TSUB + t] + red[3 * TSUB + t];
        float q = red[4 * TSUB + t] + red[5 * TSUB + t] + red[6 * TSUB + t] + red[7 * TSUB + t];
        const float mean = s * (1.f / DMODEL);
        const float var  = q * (1.f / DMODEL) - mean * mean;
        const float inv  = 1.f / sqrtf(var + LN_EPS);
        float4 o;
        o.x = (acc[t][0] - mean) * inv * g.x + bb.x;
        o.y = (acc[t][1] - mean) * inv * g.y + bb.y;
        o.z = (acc[t][2] - mean) * inv * g.z + bb.z;
        o.w = (acc[t][3] - mean) * inv * g.w + bb.w;
        *(float4*)&ybase[(size_t)t * DMODEL] = o;
    }
}

// ---------------------------------------------------------------------------
// k_state: final_state[b,n] = ((exp(dmean*A_n)-1)/A_safe_n) *
//                             sum_d B[n,d] * u[b, L-1, d]
// ---------------------------------------------------------------------------
__global__ __launch_bounds__(256) void k_state(const float* __restrict__ u,
                                               const float* __restrict__ A_log,
                                               const float* __restrict__ B,
                                               const float* __restrict__ delta,
                                               float* __restrict__ out) {
    const int n = blockIdx.x & 63;
    const int b = blockIdx.x >> 6;
    const int tid = threadIdx.x;
    const float* ul = u + ((size_t)b * SEQL + (SEQL - 1)) * DMODEL;
    const float* Bn = B + (size_t)n * DMODEL;
    float dot = 0.f, dsum = 0.f;
    for (int dd = tid; dd < DMODEL; dd += 256) {
        dot = fmaf(Bn[dd], ul[dd], dot);
        dsum += delta[dd];
    }
#pragma unroll
    for (int off = 32; off > 0; off >>= 1) {
        dot  += __shfl_down(dot,  off, 64);
        dsum += __shfl_down(dsum, off, 64);
    }
    __shared__ float red[8];
    const int wave = tid >> 6, lane = tid & 63;
    if (lane == 0) { red[wave] = dot; red[4 + wave] = dsum; }
    __syncthreads();
    if (tid == 0) {
        dot  = red[0] + red[1] + red[2] + red[3];
        dsum = red[4] + red[5] + red[6] + red[7];
        const float dmean = dsum * (1.f / DMODEL);
        const float A = -expf(A_log[n]);
        const float Abar = expf(dmean * A);
        const float Asafe = A + (A >= 0.f ? 1e-8f : -1e-8f);
        out[blockIdx.x] = ((Abar - 1.f) / Asafe) * dot;
    }
}

extern "C" void kernel_launch(void* const* d_in, const int* in_sizes, int n_in,
                              void* d_out, int out_size, void* d_ws, size_t ws_size,
                              hipStream_t stream) {
    const float* u     = (const float*)d_in[0];
    const float* A_log = (const float*)d_in[1];
    const float* B     = (const float*)d_in[2];
    const float* C     = (const float*)d_in[3];
    const float* Dv    = (const float*)d_in[4];
    const float* delta = (const float*)d_in[5];
    const float* gamma = (const float*)d_in[6];
    const float* beta  = (const float*)d_in[7];
    const float* fal   = (const float*)d_in[8];
    const float* rw    = (const float*)d_in[9];

    float* y  = (float*)d_out;
    float* st = y + (size_t)BATCH * SEQL * DMODEL;
    float* f  = (float*)d_ws;

    int NCH = 32;
    while (NCH > 4 && (size_t)BATCH * NCH * NSTATE * DMODEL * sizeof(float) > ws_size)
        NCH >>= 1;
    const int T = SEQL / NCH;

    const dim3 blk(256);
    const int nb1 = BATCH * (DMODEL / 64) * (NCH / 4);

    hipLaunchKernelGGL(k_scan, dim3(nb1), blk, 0, stream, u, A_log, C, Dv, delta, f, y, NCH, T);
    hipLaunchKernelGGL(k_pass2, dim3(BATCH * NSTATE * DMODEL / 256), blk, 0, stream,
                       A_log, delta, f, NCH, T);
    hipLaunchKernelGGL(k_corr_ln, dim3(BATCH * (SEQL / TSUB)), blk, 0, stream,
                       y, A_log, C, delta, f, gamma, beta, fal, rw, NCH, T);
    hipLaunchKernelGGL(k_state, dim3(BATCH * NSTATE), blk, 0, stream, u, A_log, B, delta, st);
}